// Round 8
// baseline (84.024 us; speedup 1.0000x reference)
//
#include <hip/hip_runtime.h>
#include <hip/hip_bf16.h>

// Linear attention (ELU feature map) via bf16 MFMA with hi/lo split-precision
// (fp32-accurate: x = hi(bf16) + lo(bf16), 3 MFMAs per product, lo*lo dropped).
//   K1 (R8): NSPL=8 -> 2048 blocks (8/CU), SINGLE-buffered 18 KB LDS,
//       no reg-prefetch (pure TLP), launch_bounds(256,8) for 64-VGPR/8-wave.
//       ksum via MFMA against all-ones B operand.
//   K2: sum partials -> O = phiQ*KV, Z via MFMA, hi/lo split (R6, verified).
// Fallback (ws too small): fp32 fused kernel (R1, verified).

constexpr int Bc = 4, Nc = 8, Hc = 8;
constexpr int Lc = 1024, Sc = 1024, Dc = 64, Mc = 64;
constexpr int HD = Hc * Dc;            // 512 floats between consecutive rows
constexpr int GROUPS = Bc * Nc * Hc;   // 256
constexpr int LSPLITS = 4;
constexpr int LROWS = Lc / LSPLITS;    // 256
constexpr int PARTIAL = Dc * Mc + Dc;  // 4160 floats per partial
constexpr int NTL = LROWS / 64;        // 4 l-tiles
constexpr int PADS = 36;               // K1 inner dim: 32 s + 4 pad (bf16)
constexpr int PADD = 68;               // K2 inner dim: 64 d + 4 pad (bf16)
constexpr float EPSF = 1e-6f;

typedef __attribute__((ext_vector_type(8))) __bf16 bf16x8;
typedef __attribute__((ext_vector_type(4))) float f32x4;

__device__ __forceinline__ float elup1(float x) {
    return x > 0.0f ? x + 1.0f : __expf(x);
}
__device__ __forceinline__ unsigned short f2bf(float f) {
    unsigned u = __builtin_bit_cast(unsigned, f);
    u += 0x7fffu + ((u >> 16) & 1u);          // round-to-nearest-even
    return (unsigned short)(u >> 16);
}
__device__ __forceinline__ float bf2f(unsigned short h) {
    return __builtin_bit_cast(float, (unsigned)h << 16);
}
// split x into hi+lo bf16 (lo = rounding residue, |lo| <= 2^-9 |x|)
__device__ __forceinline__ void splitbf(float x, unsigned short& h, unsigned short& l) {
    h = f2bf(x);
    l = f2bf(x - bf2f(h));
}
__device__ __forceinline__ unsigned pack2(unsigned short lo, unsigned short hi) {
    return (unsigned)lo | ((unsigned)hi << 16);
}
__device__ __forceinline__ bf16x8 ones_frag() {
    union { bf16x8 v; unsigned short s[8]; } u;
    #pragma unroll
    for (int i = 0; i < 8; ++i) u.s[i] = 0x3F80;   // bf16 1.0
    return u.v;
}

// ------- Kernel 1: partial KV, single-buffer LDS, high occupancy -------
template<int NSPL>
__global__ void __launch_bounds__(256, 8)
la_kv_mfma(const float* __restrict__ Kg, const float* __restrict__ Vg,
           const float* __restrict__ Mg, float* __restrict__ ws)
{
    constexpr int SR = Sc / NSPL;      // s-rows per block (128 at NSPL=8)
    constexpr int NT = SR / 32;        // tiles (4 at NSPL=8)

    __shared__ unsigned short kth[Dc][PADS];   // phiK hi   (4.5 KB)
    __shared__ unsigned short ktl[Dc][PADS];   // phiK lo
    __shared__ unsigned short vth[Dc][PADS];   // V hi
    __shared__ unsigned short vtl[Dc][PADS];   // V lo      (18 KB total)

    const int t    = threadIdx.x;
    const int tx   = t & 15;
    const int tyq  = t >> 4;       // 0..15
    const int lane = t & 63;
    const int w    = t >> 6;       // wave 0..3
    const int g    = blockIdx.y;
    const int sp   = blockIdx.x;
    const int h    = g & 7;
    const int bn   = g >> 3;
    const int b    = g >> 6;

    const size_t rowbase = (size_t)bn * Sc * HD + (size_t)h * Dc;
    const size_t mbase   = (size_t)b * Sc;
    const int    sbase   = sp * SR;

    f32x4 acc[4], aks;
    #pragma unroll
    for (int ms = 0; ms < 4; ++ms) acc[ms] = (f32x4){0.f, 0.f, 0.f, 0.f};
    aks = (f32x4){0.f, 0.f, 0.f, 0.f};
    const bf16x8 ones = ones_frag();

    const int fcol = 8 * (lane >> 4);
    const int frow = lane & 15;

    for (int it = 0; it < NT; ++it) {
        // ---- load tile (synchronous; TLP across 8 blocks/CU hides drain) ----
        const int s0 = sbase + it * 32 + 2 * tyq;
        const size_t off = rowbase + (size_t)s0 * HD + 4 * tx;
        const float4 k0 = *reinterpret_cast<const float4*>(Kg + off);
        const float4 k1 = *reinterpret_cast<const float4*>(Kg + off + HD);
        const float4 v0 = *reinterpret_cast<const float4*>(Vg + off);
        const float4 v1 = *reinterpret_cast<const float4*>(Vg + off + HD);
        const float2 m2 = *reinterpret_cast<const float2*>(Mg + mbase + s0);

        // ---- stage: phi+mask, hi/lo split, transpose to [d][s] ----
        {
            const float ka0[4] = {k0.x, k0.y, k0.z, k0.w};
            const float ka1[4] = {k1.x, k1.y, k1.z, k1.w};
            const float va0[4] = {v0.x, v0.y, v0.z, v0.w};
            const float va1[4] = {v1.x, v1.y, v1.z, v1.w};
            #pragma unroll
            for (int i = 0; i < 4; ++i) {
                const float a0 = elup1(ka0[i]) * m2.x;
                const float a1 = elup1(ka1[i]) * m2.y;
                unsigned short h0, l0, h1, l1;
                splitbf(a0, h0, l0);
                splitbf(a1, h1, l1);
                *reinterpret_cast<unsigned*>(&kth[4 * tx + i][2 * tyq]) = pack2(h0, h1);
                *reinterpret_cast<unsigned*>(&ktl[4 * tx + i][2 * tyq]) = pack2(l0, l1);
                unsigned short vh0, vl0, vh1, vl1;
                splitbf(va0[i], vh0, vl0);
                splitbf(va1[i], vh1, vl1);
                *reinterpret_cast<unsigned*>(&vth[4 * tx + i][2 * tyq]) = pack2(vh0, vh1);
                *reinterpret_cast<unsigned*>(&vtl[4 * tx + i][2 * tyq]) = pack2(vl0, vl1);
            }
        }
        __syncthreads();

        // ---- compute: fragments + MFMA ----
        {
            union { bf16x8 v; uint2 u[2]; } fah, fal;
            const uint2* ph = reinterpret_cast<const uint2*>(&kth[16 * w + frow][fcol]);
            fah.u[0] = ph[0]; fah.u[1] = ph[1];
            const uint2* pl = reinterpret_cast<const uint2*>(&ktl[16 * w + frow][fcol]);
            fal.u[0] = pl[0]; fal.u[1] = pl[1];

            aks = __builtin_amdgcn_mfma_f32_16x16x32_bf16(fah.v, ones, aks, 0, 0, 0);
            aks = __builtin_amdgcn_mfma_f32_16x16x32_bf16(fal.v, ones, aks, 0, 0, 0);
            #pragma unroll
            for (int ms = 0; ms < 4; ++ms) {
                union { bf16x8 v; uint2 u[2]; } fbh, fbl;
                const uint2* qh = reinterpret_cast<const uint2*>(&vth[16 * ms + frow][fcol]);
                fbh.u[0] = qh[0]; fbh.u[1] = qh[1];
                const uint2* ql = reinterpret_cast<const uint2*>(&vtl[16 * ms + frow][fcol]);
                fbl.u[0] = ql[0]; fbl.u[1] = ql[1];
                acc[ms] = __builtin_amdgcn_mfma_f32_16x16x32_bf16(fah.v, fbh.v, acc[ms], 0, 0, 0);
                acc[ms] = __builtin_amdgcn_mfma_f32_16x16x32_bf16(fah.v, fbl.v, acc[ms], 0, 0, 0);
                acc[ms] = __builtin_amdgcn_mfma_f32_16x16x32_bf16(fal.v, fbh.v, acc[ms], 0, 0, 0);
            }
        }
        __syncthreads();   // LDS consumed; safe to overwrite next iter
    }

    float* outp = ws + (size_t)(g * NSPL + sp) * PARTIAL;
    #pragma unroll
    for (int ms = 0; ms < 4; ++ms)
        #pragma unroll
        for (int r = 0; r < 4; ++r)
            outp[(16 * w + 4 * (lane >> 4) + r) * Mc + 16 * ms + frow] = acc[ms][r];

    // ksum: every column of aks holds ksum[d-row]; frow==0 lanes write it
    if (frow == 0) {
        #pragma unroll
        for (int r = 0; r < 4; ++r)
            outp[Dc * Mc + 16 * w + 4 * (lane >> 4) + r] = aks[r];
    }
}

// ---------------- Kernel 2: output via split-bf16 MFMA (R6, verified) --------
template<int NSPL>
__global__ void __launch_bounds__(256, 4)
la_out_mfma(const float* __restrict__ Qg, const float* __restrict__ ws,
            float* __restrict__ Og)
{
    __shared__ unsigned short kvh[Mc][PADD];  // KV hi [m][d]
    __shared__ unsigned short kvl[Mc][PADD];  // KV lo
    __shared__ unsigned short ksh[64];        // ksum hi
    __shared__ unsigned short ksl[64];        // ksum lo
    __shared__ unsigned short qhh[64][PADD];  // phiQ hi [l][d]
    __shared__ unsigned short qll[64][PADD];  // phiQ lo

    const int t    = threadIdx.x;
    const int tx   = t & 15;
    const int tyq  = t >> 4;
    const int lane = t & 63;
    const int w    = t >> 6;
    const int g    = blockIdx.y;
    const int ls   = blockIdx.x;
    const int h    = g & 7;
    const int bn   = g >> 3;

    const size_t rowbase = (size_t)bn * Lc * HD + (size_t)h * Dc;
    const float* pw = ws + (size_t)g * NSPL * PARTIAL;
    const int lbase = ls * LROWS;

    float4 qr[4];
    auto loadB = [&](int it) {
        const int l0 = lbase + it * 64 + 4 * tyq;
        #pragma unroll
        for (int j = 0; j < 4; ++j)
            qr[j] = *reinterpret_cast<const float4*>(Qg + rowbase + (size_t)(l0 + j) * HD + 4 * tx);
    };
    auto storeB = [&]() {
        #pragma unroll
        for (int j = 0; j < 4; ++j) {
            const int r = 4 * tyq + j;
            const float q[4] = {qr[j].x, qr[j].y, qr[j].z, qr[j].w};
            unsigned short h0, l0, h1, l1, h2, l2, h3, l3;
            splitbf(elup1(q[0]), h0, l0);
            splitbf(elup1(q[1]), h1, l1);
            splitbf(elup1(q[2]), h2, l2);
            splitbf(elup1(q[3]), h3, l3);
            uint2 ph, pl;
            ph.x = pack2(h0, h1); ph.y = pack2(h2, h3);
            pl.x = pack2(l0, l1); pl.y = pack2(l2, l3);
            *reinterpret_cast<uint2*>(&qhh[r][4 * tx]) = ph;
            *reinterpret_cast<uint2*>(&qll[r][4 * tx]) = pl;
        }
    };

    loadB(0);
    // sum the NSPL partials; split into hi/lo, transpose into [m][d]
    #pragma unroll
    for (int e = 0; e < 16; ++e) {
        const int idx = t + 256 * e;
        float s = 0.f;
        #pragma unroll
        for (int sp = 0; sp < NSPL; ++sp) s += pw[sp * PARTIAL + idx];
        unsigned short hh, ll;
        splitbf(s, hh, ll);
        kvh[idx & 63][idx >> 6] = hh;
        kvl[idx & 63][idx >> 6] = ll;
    }
    if (t < 64) {
        float s = 0.f;
        #pragma unroll
        for (int sp = 0; sp < NSPL; ++sp) s += pw[sp * PARTIAL + Dc * Mc + t];
        unsigned short hh, ll;
        splitbf(s, hh, ll);
        ksh[t] = hh;
        ksl[t] = ll;
    }
    storeB();
    __syncthreads();

    const int fcol = 8 * (lane >> 4);
    const int frow = lane & 15;
    const size_t obase = (size_t)bn * Lc * HD + (size_t)h * Mc;

    for (int it = 0; it < NTL; ++it) {
        if (it + 1 < NTL) loadB(it + 1);
        union { bf16x8 v; uint2 u[2]; } fah0, fal0, fah1, fal1;
        {
            const uint2* p;
            p = reinterpret_cast<const uint2*>(&qhh[16 * w + frow][fcol]);      fah0.u[0] = p[0]; fah0.u[1] = p[1];
            p = reinterpret_cast<const uint2*>(&qll[16 * w + frow][fcol]);      fal0.u[0] = p[0]; fal0.u[1] = p[1];
            p = reinterpret_cast<const uint2*>(&qhh[16 * w + frow][32 + fcol]); fah1.u[0] = p[0]; fah1.u[1] = p[1];
            p = reinterpret_cast<const uint2*>(&qll[16 * w + frow][32 + fcol]); fal1.u[0] = p[0]; fal1.u[1] = p[1];
        }
        f32x4 acc[4], accz;
        #pragma unroll
        for (int ms = 0; ms < 4; ++ms) acc[ms] = (f32x4){0.f, 0.f, 0.f, 0.f};
        accz = (f32x4){0.f, 0.f, 0.f, 0.f};

        #pragma unroll
        for (int ks = 0; ks < 2; ++ks) {
            const bf16x8 fh = ks ? fah1.v : fah0.v;
            const bf16x8 fl = ks ? fal1.v : fal0.v;
            #pragma unroll
            for (int ms = 0; ms < 4; ++ms) {
                union { bf16x8 v; uint2 u[2]; } fbh, fbl;
                const uint2* ph = reinterpret_cast<const uint2*>(&kvh[16 * ms + frow][32 * ks + fcol]);
                fbh.u[0] = ph[0]; fbh.u[1] = ph[1];
                const uint2* pl = reinterpret_cast<const uint2*>(&kvl[16 * ms + frow][32 * ks + fcol]);
                fbl.u[0] = pl[0]; fbl.u[1] = pl[1];
                acc[ms] = __builtin_amdgcn_mfma_f32_16x16x32_bf16(fh, fbh.v, acc[ms], 0, 0, 0);
                acc[ms] = __builtin_amdgcn_mfma_f32_16x16x32_bf16(fh, fbl.v, acc[ms], 0, 0, 0);
                acc[ms] = __builtin_amdgcn_mfma_f32_16x16x32_bf16(fl, fbh.v, acc[ms], 0, 0, 0);
            }
            union { bf16x8 v; uint2 u[2]; } fzh, fzl;
            const uint2* ph = reinterpret_cast<const uint2*>(&ksh[32 * ks + fcol]);
            fzh.u[0] = ph[0]; fzh.u[1] = ph[1];
            const uint2* pl = reinterpret_cast<const uint2*>(&ksl[32 * ks + fcol]);
            fzl.u[0] = pl[0]; fzl.u[1] = pl[1];
            accz = __builtin_amdgcn_mfma_f32_16x16x32_bf16(fh, fzh.v, accz, 0, 0, 0);
            accz = __builtin_amdgcn_mfma_f32_16x16x32_bf16(fh, fzl.v, accz, 0, 0, 0);
            accz = __builtin_amdgcn_mfma_f32_16x16x32_bf16(fl, fzh.v, accz, 0, 0, 0);
        }

        const int lt = lbase + it * 64 + 16 * w + 4 * (lane >> 4);
        #pragma unroll
        for (int r = 0; r < 4; ++r) {
            const float z = 1.0f / (accz[r] + EPSF);
            const size_t ro = obase + (size_t)(lt + r) * HD + frow;
            #pragma unroll
            for (int ms = 0; ms < 4; ++ms)
                Og[ro + 16 * ms] = acc[ms][r] * z;
        }
        __syncthreads();
        if (it + 1 < NTL) storeB();
        __syncthreads();
    }
}

// ---------------- Fallback: fp32 fused kernel (verified R1) ----------------
__global__ void __launch_bounds__(256, 1)
la_fused_kernel(const float* __restrict__ Qg, const float* __restrict__ Kg,
                const float* __restrict__ Vg, const float* __restrict__ Mg,
                float* __restrict__ Og)
{
    __shared__ float lk[32][Dc];
    __shared__ float lv[32][Mc];
    __shared__ float kvt[Dc][Mc];
    __shared__ float ksm[Dc];
    __shared__ float qt[Dc][64];

    const int t  = threadIdx.x;
    const int tx = t & 15;
    const int ty = t >> 4;
    const int g  = blockIdx.x;
    const int h  = g & 7;
    const int bn = g >> 3;
    const int b  = g >> 6;

    const size_t rowbase = (size_t)bn * Sc * HD + (size_t)h * Dc;
    const size_t mbase   = (size_t)b * Sc;

    const int d0 = tx * 4, m0 = ty * 4, c4 = tx * 4, r0 = ty;

    float acc[4][4] = {{0.f,0.f,0.f,0.f},{0.f,0.f,0.f,0.f},{0.f,0.f,0.f,0.f},{0.f,0.f,0.f,0.f}};
    float ks[4] = {0.f, 0.f, 0.f, 0.f};
    float4 kr[2], vr[2];
    float  mr[2];

    auto loadA = [&](int it) {
        const int s0 = it * 32;
        #pragma unroll
        for (int k = 0; k < 2; ++k) {
            const int r = r0 + 16 * k;
            const size_t off = rowbase + (size_t)(s0 + r) * HD + c4;
            kr[k] = *reinterpret_cast<const float4*>(Kg + off);
            vr[k] = *reinterpret_cast<const float4*>(Vg + off);
            mr[k] = Mg[mbase + s0 + r];
        }
    };
    auto storeA = [&]() {
        #pragma unroll
        for (int k = 0; k < 2; ++k) {
            const int r = r0 + 16 * k;
            float4 kk;
            kk.x = elup1(kr[k].x) * mr[k];
            kk.y = elup1(kr[k].y) * mr[k];
            kk.z = elup1(kr[k].z) * mr[k];
            kk.w = elup1(kr[k].w) * mr[k];
            *reinterpret_cast<float4*>(&lk[r][c4]) = kk;
            *reinterpret_cast<float4*>(&lv[r][c4]) = vr[k];
        }
    };

    loadA(0);
    storeA();
    __syncthreads();
    for (int it = 0; it < Sc / 32; ++it) {
        if (it + 1 < Sc / 32) loadA(it + 1);
        #pragma unroll 8
        for (int r = 0; r < 32; ++r) {
            const float4 k4 = *reinterpret_cast<const float4*>(&lk[r][d0]);
            const float4 v4 = *reinterpret_cast<const float4*>(&lv[r][m0]);
            const float kk[4] = {k4.x, k4.y, k4.z, k4.w};
            const float vv[4] = {v4.x, v4.y, v4.z, v4.w};
            ks[0] += kk[0]; ks[1] += kk[1]; ks[2] += kk[2]; ks[3] += kk[3];
            #pragma unroll
            for (int i = 0; i < 4; ++i)
                #pragma unroll
                for (int j = 0; j < 4; ++j)
                    acc[i][j] += kk[i] * vv[j];
        }
        __syncthreads();
        if (it + 1 < Sc / 32) storeA();
        __syncthreads();
    }

    #pragma unroll
    for (int i = 0; i < 4; ++i) {
        float4 w;
        w.x = acc[i][0]; w.y = acc[i][1]; w.z = acc[i][2]; w.w = acc[i][3];
        *reinterpret_cast<float4*>(&kvt[d0 + i][m0]) = w;
    }
    if (ty == 0) {
        #pragma unroll
        for (int i = 0; i < 4; ++i) ksm[d0 + i] = ks[i];
    }
    __syncthreads();

    float4 qr[4];
    auto loadB = [&](int it) {
        const int l0 = it * 64;
        #pragma unroll
        for (int k = 0; k < 4; ++k) {
            const int r = r0 + 16 * k;
            const size_t off = rowbase + (size_t)(l0 + r) * HD + c4;
            qr[k] = *reinterpret_cast<const float4*>(Qg + off);
        }
    };
    const int swzw = (tx & 7) << 2;
    auto storeB = [&]() {
        #pragma unroll
        for (int k = 0; k < 4; ++k) {
            const int r = r0 + 16 * k;
            const int lidx = r ^ swzw;
            qt[c4 + 0][lidx] = elup1(qr[k].x);
            qt[c4 + 1][lidx] = elup1(qr[k].y);
            qt[c4 + 2][lidx] = elup1(qr[k].z);
            qt[c4 + 3][lidx] = elup1(qr[k].w);
        }
    };

    loadB(0);
    storeB();
    __syncthreads();
    for (int it = 0; it < Lc / 64; ++it) {
        if (it + 1 < Lc / 64) loadB(it + 1);
        float accB[4][4] = {{0.f,0.f,0.f,0.f},{0.f,0.f,0.f,0.f},{0.f,0.f,0.f,0.f},{0.f,0.f,0.f,0.f}};
        float za[4] = {0.f, 0.f, 0.f, 0.f};
        #pragma unroll 8
        for (int d = 0; d < Dc; ++d) {
            const int swz = ((d >> 2) & 7) << 2;
            const float4 q4  = *reinterpret_cast<const float4*>(&qt[d][(4 * ty) ^ swz]);
            const float4 kv4 = *reinterpret_cast<const float4*>(&kvt[d][4 * tx]);
            const float kd = ksm[d];
            const float qq[4] = {q4.x, q4.y, q4.z, q4.w};
            const float kv[4] = {kv4.x, kv4.y, kv4.z, kv4.w};
            #pragma unroll
            for (int i = 0; i < 4; ++i) {
                za[i] += qq[i] * kd;
                #pragma unroll
                for (int j = 0; j < 4; ++j)
                    accB[i][j] += qq[i] * kv[j];
            }
        }
        const int l0 = it * 64;
        const size_t obase = (size_t)bn * Lc * HD + (size_t)h * Mc;
        #pragma unroll
        for (int i = 0; i < 4; ++i) {
            const int l = l0 + 4 * ty + i;
            const float z = 1.0f / (za[i] + EPSF);
            float4 o;
            o.x = accB[i][0] * z; o.y = accB[i][1] * z;
            o.z = accB[i][2] * z; o.w = accB[i][3] * z;
            *reinterpret_cast<float4*>(Og + obase + (size_t)l * HD + 4 * tx) = o;
        }
        __syncthreads();
        if (it + 1 < Lc / 64) storeB();
        __syncthreads();
    }
}

extern "C" void kernel_launch(void* const* d_in, const int* in_sizes, int n_in,
                              void* d_out, int out_size, void* d_ws, size_t ws_size,
                              hipStream_t stream) {
    const float* Qg = (const float*)d_in[0];
    const float* Kg = (const float*)d_in[1];
    const float* Vg = (const float*)d_in[2];
    const float* Mg = (const float*)d_in[3];
    float* Og = (float*)d_out;

    const size_t need8 = (size_t)GROUPS * 8 * PARTIAL * sizeof(float);
    const size_t need4 = (size_t)GROUPS * 4 * PARTIAL * sizeof(float);
    if (ws_size >= need8) {
        float* ws = (float*)d_ws;
        hipLaunchKernelGGL((la_kv_mfma<8>), dim3(8, GROUPS), dim3(256), 0, stream,
                           Kg, Vg, Mg, ws);
        hipLaunchKernelGGL((la_out_mfma<8>), dim3(LSPLITS, GROUPS), dim3(256), 0, stream,
                           Qg, ws, Og);
    } else if (ws_size >= need4) {
        float* ws = (float*)d_ws;
        hipLaunchKernelGGL((la_kv_mfma<4>), dim3(4, GROUPS), dim3(256), 0, stream,
                           Kg, Vg, Mg, ws);
        hipLaunchKernelGGL((la_out_mfma<4>), dim3(LSPLITS, GROUPS), dim3(256), 0, stream,
                           Qg, ws, Og);
    } else {
        hipLaunchKernelGGL(la_fused_kernel, dim3(GROUPS), dim3(256), 0, stream,
                           Qg, Kg, Vg, Mg, Og);
    }
}

// Round 9
// 79.575 us; speedup vs baseline: 1.0559x; 1.0559x over previous
//
#include <hip/hip_runtime.h>
#include <hip/hip_bf16.h>

// Linear attention (ELU feature map) via bf16 MFMA with hi/lo split-precision.
//   K1 (R9): global_load_lds DMA pipeline, depth 3, RAW s_barrier + counted
//       inline-asm vmcnt (never drained to 0 in steady state). fp32 tiles in
//       LDS [32][64]; fragments gathered via ds_read_b32; hi/lo split in regs;
//       ksum via MFMA against all-ones B. NSPL=4.
//   K2: sum partials -> O = phiQ*KV, Z via MFMA, hi/lo split (R6, verified).
// Fallback (ws too small): fp32 fused kernel (R1, verified).

constexpr int Bc = 4, Nc = 8, Hc = 8;
constexpr int Lc = 1024, Sc = 1024, Dc = 64, Mc = 64;
constexpr int HD = Hc * Dc;            // 512 floats between consecutive rows
constexpr int GROUPS = Bc * Nc * Hc;   // 256
constexpr int LSPLITS = 4;
constexpr int LROWS = Lc / LSPLITS;    // 256
constexpr int PARTIAL = Dc * Mc + Dc;  // 4160 floats per partial
constexpr int NTL = LROWS / 64;        // 4 l-tiles
constexpr int PADD = 68;               // K2 inner dim: 64 d + 4 pad (bf16)
constexpr float EPSF = 1e-6f;

typedef __attribute__((ext_vector_type(8))) __bf16 bf16x8;
typedef __attribute__((ext_vector_type(4))) float f32x4;

#define AS1C const __attribute__((address_space(1))) void*
#define AS3  __attribute__((address_space(3))) void*

__device__ __forceinline__ float elup1(float x) {
    return x > 0.0f ? x + 1.0f : __expf(x);
}
__device__ __forceinline__ unsigned short f2bf(float f) {
    unsigned u = __builtin_bit_cast(unsigned, f);
    u += 0x7fffu + ((u >> 16) & 1u);          // round-to-nearest-even
    return (unsigned short)(u >> 16);
}
__device__ __forceinline__ float bf2f(unsigned short h) {
    return __builtin_bit_cast(float, (unsigned)h << 16);
}
__device__ __forceinline__ void splitbf(float x, unsigned short& h, unsigned short& l) {
    h = f2bf(x);
    l = f2bf(x - bf2f(h));
}
__device__ __forceinline__ unsigned pack2(unsigned short lo, unsigned short hi) {
    return (unsigned)lo | ((unsigned)hi << 16);
}
__device__ __forceinline__ bf16x8 ones_frag() {
    union { bf16x8 v; unsigned short s[8]; } u;
    #pragma unroll
    for (int i = 0; i < 8; ++i) u.s[i] = 0x3F80;   // bf16 1.0
    return u.v;
}

// ------- Kernel 1: partial KV, DMA-pipelined (depth 3, counted vmcnt) -------
template<int NSPL>
__global__ void __launch_bounds__(256, 4)
la_kv_dma(const float* __restrict__ Kg, const float* __restrict__ Vg,
          const float* __restrict__ Mg, float* __restrict__ ws)
{
    constexpr int SR = Sc / NSPL;      // 256 s-rows per block
    constexpr int NT = SR / 32;        // 8 tiles

    __shared__ float kf[3][32][64];    // 3 x 8 KB, DMA dest (contiguous!)
    __shared__ float vf[3][32][64];    // 3 x 8 KB
    __shared__ float mlds[SR];         // 1 KB mask

    const int t    = threadIdx.x;
    const int lane = t & 63;
    const int w    = t >> 6;           // wave 0..3
    const int frow = lane & 15;
    const int kg   = lane >> 4;        // k-group 0..3
    const int g    = blockIdx.y;
    const int sp   = blockIdx.x;
    const int h    = g & 7;
    const int bn   = g >> 3;
    const int b    = g >> 6;

    const size_t rowbase = (size_t)bn * Sc * HD + (size_t)h * Dc;
    const int    sbase   = sp * SR;

    // prologue: mask -> LDS with normal loads (fully drained before any DMA)
    if (t < SR) mlds[t] = Mg[(size_t)b * Sc + sbase + t];
    __syncthreads();

    // DMA: wave w owns s-rows 8w..8w+7 of each tile; 2 instrs/tensor/tile.
    // lane l of an instr loads global row (slab + l>>4), cols (l&15)*4..+3;
    // lands at LDS base + 16*l  ==  [slab + l>>4][(l&15)*4] of [32][64] fp32.
    const int drow = lane >> 4;
    const int dcol = (lane & 15) * 4;

    auto issue = [&](int it, int buf) {
        const int s0 = sbase + it * 32 + 8 * w;
        #pragma unroll
        for (int q = 0; q < 2; ++q) {
            const int r = 4 * q;
            const float* gk = Kg + rowbase + (size_t)(s0 + r + drow) * HD + dcol;
            const float* gv = Vg + rowbase + (size_t)(s0 + r + drow) * HD + dcol;
            __builtin_amdgcn_global_load_lds((AS1C)gk, (AS3)&kf[buf][8 * w + r][0], 16, 0, 0);
            __builtin_amdgcn_global_load_lds((AS1C)gv, (AS3)&vf[buf][8 * w + r][0], 16, 0, 0);
        }
    };

    f32x4 acc[4], aks;
    #pragma unroll
    for (int ms = 0; ms < 4; ++ms) acc[ms] = (f32x4){0.f, 0.f, 0.f, 0.f};
    aks = (f32x4){0.f, 0.f, 0.f, 0.f};
    const bf16x8 ones = ones_frag();

    union uf { bf16x8 v; unsigned short s[8]; };

    auto compute = [&](int it, int buf) {
        // A fragment: K[s=8kg+j][d=16w+frow], j=0..7  (+ mask, elu, hi/lo)
        float ka[8], ml[8];
        #pragma unroll
        for (int j = 0; j < 8; ++j) {
            ka[j] = kf[buf][8 * kg + j][16 * w + frow];
            ml[j] = mlds[it * 32 + 8 * kg + j];
        }
        uf kh, kl;
        #pragma unroll
        for (int j = 0; j < 8; ++j)
            splitbf(elup1(ka[j]) * ml[j], kh.s[j], kl.s[j]);
        aks = __builtin_amdgcn_mfma_f32_16x16x32_bf16(kh.v, ones, aks, 0, 0, 0);
        aks = __builtin_amdgcn_mfma_f32_16x16x32_bf16(kl.v, ones, aks, 0, 0, 0);
        #pragma unroll
        for (int ms = 0; ms < 4; ++ms) {
            float vb[8];
            #pragma unroll
            for (int j = 0; j < 8; ++j)
                vb[j] = vf[buf][8 * kg + j][16 * ms + frow];
            uf vh, vl;
            #pragma unroll
            for (int j = 0; j < 8; ++j)
                splitbf(vb[j], vh.s[j], vl.s[j]);
            acc[ms] = __builtin_amdgcn_mfma_f32_16x16x32_bf16(kh.v, vh.v, acc[ms], 0, 0, 0);
            acc[ms] = __builtin_amdgcn_mfma_f32_16x16x32_bf16(kh.v, vl.v, acc[ms], 0, 0, 0);
            acc[ms] = __builtin_amdgcn_mfma_f32_16x16x32_bf16(kl.v, vh.v, acc[ms], 0, 0, 0);
        }
    };

    // fill the pipe: 3 tiles in flight (12 DMA instrs/wave)
    issue(0, 0);
    if (NT > 1) issue(1, 1);
    if (NT > 2) issue(2, 2);

    for (int it = 0; it < NT; ++it) {
        const int buf = it % 3;
        const int rem = NT - 1 - it;     // tiles still outstanding beyond it
        // wait for MY tile-it DMAs (leave newer tiles in flight!)
        if (rem >= 2)      asm volatile("s_waitcnt vmcnt(8)" ::: "memory");
        else if (rem == 1) asm volatile("s_waitcnt vmcnt(4)" ::: "memory");
        else               asm volatile("s_waitcnt vmcnt(0)" ::: "memory");
        __builtin_amdgcn_sched_barrier(0);
        __builtin_amdgcn_s_barrier();    // now ALL waves' tile-it DMAs visible
        compute(it, buf);
        __builtin_amdgcn_s_barrier();    // all waves done reading buf
        if (it + 3 < NT) issue(it + 3, buf);
    }

    float* outp = ws + (size_t)(g * NSPL + sp) * PARTIAL;
    #pragma unroll
    for (int ms = 0; ms < 4; ++ms)
        #pragma unroll
        for (int r = 0; r < 4; ++r)
            outp[(16 * w + 4 * kg + r) * Mc + 16 * ms + frow] = acc[ms][r];

    if (frow == 0) {
        #pragma unroll
        for (int r = 0; r < 4; ++r)
            outp[Dc * Mc + 16 * w + 4 * kg + r] = aks[r];
    }
}

// ---------------- Kernel 2: output via split-bf16 MFMA (R6, verified) --------
template<int NSPL>
__global__ void __launch_bounds__(256, 4)
la_out_mfma(const float* __restrict__ Qg, const float* __restrict__ ws,
            float* __restrict__ Og)
{
    __shared__ unsigned short kvh[Mc][PADD];  // KV hi [m][d]
    __shared__ unsigned short kvl[Mc][PADD];  // KV lo
    __shared__ unsigned short ksh[64];        // ksum hi
    __shared__ unsigned short ksl[64];        // ksum lo
    __shared__ unsigned short qhh[64][PADD];  // phiQ hi [l][d]
    __shared__ unsigned short qll[64][PADD];  // phiQ lo

    const int t    = threadIdx.x;
    const int tx   = t & 15;
    const int tyq  = t >> 4;
    const int lane = t & 63;
    const int w    = t >> 6;
    const int g    = blockIdx.y;
    const int ls   = blockIdx.x;
    const int h    = g & 7;
    const int bn   = g >> 3;

    const size_t rowbase = (size_t)bn * Lc * HD + (size_t)h * Dc;
    const float* pw = ws + (size_t)g * NSPL * PARTIAL;
    const int lbase = ls * LROWS;

    float4 qr[4];
    auto loadB = [&](int it) {
        const int l0 = lbase + it * 64 + 4 * tyq;
        #pragma unroll
        for (int j = 0; j < 4; ++j)
            qr[j] = *reinterpret_cast<const float4*>(Qg + rowbase + (size_t)(l0 + j) * HD + 4 * tx);
    };
    auto storeB = [&]() {
        #pragma unroll
        for (int j = 0; j < 4; ++j) {
            const int r = 4 * tyq + j;
            const float q[4] = {qr[j].x, qr[j].y, qr[j].z, qr[j].w};
            unsigned short h0, l0, h1, l1, h2, l2, h3, l3;
            splitbf(elup1(q[0]), h0, l0);
            splitbf(elup1(q[1]), h1, l1);
            splitbf(elup1(q[2]), h2, l2);
            splitbf(elup1(q[3]), h3, l3);
            uint2 ph, pl;
            ph.x = pack2(h0, h1); ph.y = pack2(h2, h3);
            pl.x = pack2(l0, l1); pl.y = pack2(l2, l3);
            *reinterpret_cast<uint2*>(&qhh[r][4 * tx]) = ph;
            *reinterpret_cast<uint2*>(&qll[r][4 * tx]) = pl;
        }
    };

    loadB(0);
    #pragma unroll
    for (int e = 0; e < 16; ++e) {
        const int idx = t + 256 * e;
        float s = 0.f;
        #pragma unroll
        for (int sp = 0; sp < NSPL; ++sp) s += pw[sp * PARTIAL + idx];
        unsigned short hh, ll;
        splitbf(s, hh, ll);
        kvh[idx & 63][idx >> 6] = hh;
        kvl[idx & 63][idx >> 6] = ll;
    }
    if (t < 64) {
        float s = 0.f;
        #pragma unroll
        for (int sp = 0; sp < NSPL; ++sp) s += pw[sp * PARTIAL + Dc * Mc + t];
        unsigned short hh, ll;
        splitbf(s, hh, ll);
        ksh[t] = hh;
        ksl[t] = ll;
    }
    storeB();
    __syncthreads();

    const int fcol = 8 * (lane >> 4);
    const int frow = lane & 15;
    const size_t obase = (size_t)bn * Lc * HD + (size_t)h * Mc;

    for (int it = 0; it < NTL; ++it) {
        if (it + 1 < NTL) loadB(it + 1);
        union { bf16x8 v; uint2 u[2]; } fah0, fal0, fah1, fal1;
        {
            const uint2* p;
            p = reinterpret_cast<const uint2*>(&qhh[16 * w + frow][fcol]);      fah0.u[0] = p[0]; fah0.u[1] = p[1];
            p = reinterpret_cast<const uint2*>(&qll[16 * w + frow][fcol]);      fal0.u[0] = p[0]; fal0.u[1] = p[1];
            p = reinterpret_cast<const uint2*>(&qhh[16 * w + frow][32 + fcol]); fah1.u[0] = p[0]; fah1.u[1] = p[1];
            p = reinterpret_cast<const uint2*>(&qll[16 * w + frow][32 + fcol]); fal1.u[0] = p[0]; fal1.u[1] = p[1];
        }
        f32x4 acc[4], accz;
        #pragma unroll
        for (int ms = 0; ms < 4; ++ms) acc[ms] = (f32x4){0.f, 0.f, 0.f, 0.f};
        accz = (f32x4){0.f, 0.f, 0.f, 0.f};

        #pragma unroll
        for (int ks = 0; ks < 2; ++ks) {
            const bf16x8 fh = ks ? fah1.v : fah0.v;
            const bf16x8 fl = ks ? fal1.v : fal0.v;
            #pragma unroll
            for (int ms = 0; ms < 4; ++ms) {
                union { bf16x8 v; uint2 u[2]; } fbh, fbl;
                const uint2* ph = reinterpret_cast<const uint2*>(&kvh[16 * ms + frow][32 * ks + fcol]);
                fbh.u[0] = ph[0]; fbh.u[1] = ph[1];
                const uint2* pl = reinterpret_cast<const uint2*>(&kvl[16 * ms + frow][32 * ks + fcol]);
                fbl.u[0] = pl[0]; fbl.u[1] = pl[1];
                acc[ms] = __builtin_amdgcn_mfma_f32_16x16x32_bf16(fh, fbh.v, acc[ms], 0, 0, 0);
                acc[ms] = __builtin_amdgcn_mfma_f32_16x16x32_bf16(fh, fbl.v, acc[ms], 0, 0, 0);
                acc[ms] = __builtin_amdgcn_mfma_f32_16x16x32_bf16(fl, fbh.v, acc[ms], 0, 0, 0);
            }
            union { bf16x8 v; uint2 u[2]; } fzh, fzl;
            const uint2* ph = reinterpret_cast<const uint2*>(&ksh[32 * ks + fcol]);
            fzh.u[0] = ph[0]; fzh.u[1] = ph[1];
            const uint2* pl = reinterpret_cast<const uint2*>(&ksl[32 * ks + fcol]);
            fzl.u[0] = pl[0]; fzl.u[1] = pl[1];
            accz = __builtin_amdgcn_mfma_f32_16x16x32_bf16(fh, fzh.v, accz, 0, 0, 0);
            accz = __builtin_amdgcn_mfma_f32_16x16x32_bf16(fh, fzl.v, accz, 0, 0, 0);
            accz = __builtin_amdgcn_mfma_f32_16x16x32_bf16(fl, fzh.v, accz, 0, 0, 0);
        }

        const int lt = lbase + it * 64 + 16 * w + 4 * (lane >> 4);
        #pragma unroll
        for (int r = 0; r < 4; ++r) {
            const float z = 1.0f / (accz[r] + EPSF);
            const size_t ro = obase + (size_t)(lt + r) * HD + frow;
            #pragma unroll
            for (int ms = 0; ms < 4; ++ms)
                Og[ro + 16 * ms] = acc[ms][r] * z;
        }
        __syncthreads();
        if (it + 1 < NTL) storeB();
        __syncthreads();
    }
}

// ---------------- Fallback: fp32 fused kernel (verified R1) ----------------
__global__ void __launch_bounds__(256, 1)
la_fused_kernel(const float* __restrict__ Qg, const float* __restrict__ Kg,
                const float* __restrict__ Vg, const float* __restrict__ Mg,
                float* __restrict__ Og)
{
    __shared__ float lk[32][Dc];
    __shared__ float lv[32][Mc];
    __shared__ float kvt[Dc][Mc];
    __shared__ float ksm[Dc];
    __shared__ float qt[Dc][64];

    const int t  = threadIdx.x;
    const int tx = t & 15;
    const int ty = t >> 4;
    const int g  = blockIdx.x;
    const int h  = g & 7;
    const int bn = g >> 3;
    const int b  = g >> 6;

    const size_t rowbase = (size_t)bn * Sc * HD + (size_t)h * Dc;
    const size_t mbase   = (size_t)b * Sc;

    const int d0 = tx * 4, m0 = ty * 4, c4 = tx * 4, r0 = ty;

    float acc[4][4] = {{0.f,0.f,0.f,0.f},{0.f,0.f,0.f,0.f},{0.f,0.f,0.f,0.f},{0.f,0.f,0.f,0.f}};
    float ks[4] = {0.f, 0.f, 0.f, 0.f};
    float4 kr[2], vr[2];
    float  mr[2];

    auto loadA = [&](int it) {
        const int s0 = it * 32;
        #pragma unroll
        for (int k = 0; k < 2; ++k) {
            const int r = r0 + 16 * k;
            const size_t off = rowbase + (size_t)(s0 + r) * HD + c4;
            kr[k] = *reinterpret_cast<const float4*>(Kg + off);
            vr[k] = *reinterpret_cast<const float4*>(Vg + off);
            mr[k] = Mg[mbase + s0 + r];
        }
    };
    auto storeA = [&]() {
        #pragma unroll
        for (int k = 0; k < 2; ++k) {
            const int r = r0 + 16 * k;
            float4 kk;
            kk.x = elup1(kr[k].x) * mr[k];
            kk.y = elup1(kr[k].y) * mr[k];
            kk.z = elup1(kr[k].z) * mr[k];
            kk.w = elup1(kr[k].w) * mr[k];
            *reinterpret_cast<float4*>(&lk[r][c4]) = kk;
            *reinterpret_cast<float4*>(&lv[r][c4]) = vr[k];
        }
    };

    loadA(0);
    storeA();
    __syncthreads();
    for (int it = 0; it < Sc / 32; ++it) {
        if (it + 1 < Sc / 32) loadA(it + 1);
        #pragma unroll 8
        for (int r = 0; r < 32; ++r) {
            const float4 k4 = *reinterpret_cast<const float4*>(&lk[r][d0]);
            const float4 v4 = *reinterpret_cast<const float4*>(&lv[r][m0]);
            const float kk[4] = {k4.x, k4.y, k4.z, k4.w};
            const float vv[4] = {v4.x, v4.y, v4.z, v4.w};
            ks[0] += kk[0]; ks[1] += kk[1]; ks[2] += kk[2]; ks[3] += kk[3];
            #pragma unroll
            for (int i = 0; i < 4; ++i)
                #pragma unroll
                for (int j = 0; j < 4; ++j)
                    acc[i][j] += kk[i] * vv[j];
        }
        __syncthreads();
        if (it + 1 < Sc / 32) storeA();
        __syncthreads();
    }

    #pragma unroll
    for (int i = 0; i < 4; ++i) {
        float4 w;
        w.x = acc[i][0]; w.y = acc[i][1]; w.z = acc[i][2]; w.w = acc[i][3];
        *reinterpret_cast<float4*>(&kvt[d0 + i][m0]) = w;
    }
    if (ty == 0) {
        #pragma unroll
        for (int i = 0; i < 4; ++i) ksm[d0 + i] = ks[i];
    }
    __syncthreads();

    float4 qr[4];
    auto loadB = [&](int it) {
        const int l0 = it * 64;
        #pragma unroll
        for (int k = 0; k < 4; ++k) {
            const int r = r0 + 16 * k;
            const size_t off = rowbase + (size_t)(l0 + r) * HD + c4;
            qr[k] = *reinterpret_cast<const float4*>(Qg + off);
        }
    };
    const int swzw = (tx & 7) << 2;
    auto storeB = [&]() {
        #pragma unroll
        for (int k = 0; k < 4; ++k) {
            const int r = r0 + 16 * k;
            const int lidx = r ^ swzw;
            qt[c4 + 0][lidx] = elup1(qr[k].x);
            qt[c4 + 1][lidx] = elup1(qr[k].y);
            qt[c4 + 2][lidx] = elup1(qr[k].z);
            qt[c4 + 3][lidx] = elup1(qr[k].w);
        }
    };

    loadB(0);
    storeB();
    __syncthreads();
    for (int it = 0; it < Lc / 64; ++it) {
        if (it + 1 < Lc / 64) loadB(it + 1);
        float accB[4][4] = {{0.f,0.f,0.f,0.f},{0.f,0.f,0.f,0.f},{0.f,0.f,0.f,0.f},{0.f,0.f,0.f,0.f}};
        float za[4] = {0.f, 0.f, 0.f, 0.f};
        #pragma unroll 8
        for (int d = 0; d < Dc; ++d) {
            const int swz = ((d >> 2) & 7) << 2;
            const float4 q4  = *reinterpret_cast<const float4*>(&qt[d][(4 * ty) ^ swz]);
            const float4 kv4 = *reinterpret_cast<const float4*>(&kvt[d][4 * tx]);
            const float kd = ksm[d];
            const float qq[4] = {q4.x, q4.y, q4.z, q4.w};
            const float kv[4] = {kv4.x, kv4.y, kv4.z, kv4.w};
            #pragma unroll
            for (int i = 0; i < 4; ++i) {
                za[i] += qq[i] * kd;
                #pragma unroll
                for (int j = 0; j < 4; ++j)
                    accB[i][j] += qq[i] * kv[j];
            }
        }
        const int l0 = it * 64;
        const size_t obase = (size_t)bn * Lc * HD + (size_t)h * Mc;
        #pragma unroll
        for (int i = 0; i < 4; ++i) {
            const int l = l0 + 4 * ty + i;
            const float z = 1.0f / (za[i] + EPSF);
            float4 o;
            o.x = accB[i][0] * z; o.y = accB[i][1] * z;
            o.z = accB[i][2] * z; o.w = accB[i][3] * z;
            *reinterpret_cast<float4*>(Og + obase + (size_t)l * HD + 4 * tx) = o;
        }
        __syncthreads();
        if (it + 1 < Lc / 64) storeB();
        __syncthreads();
    }
}

extern "C" void kernel_launch(void* const* d_in, const int* in_sizes, int n_in,
                              void* d_out, int out_size, void* d_ws, size_t ws_size,
                              hipStream_t stream) {
    const float* Qg = (const float*)d_in[0];
    const float* Kg = (const float*)d_in[1];
    const float* Vg = (const float*)d_in[2];
    const float* Mg = (const float*)d_in[3];
    float* Og = (float*)d_out;

    const size_t need4 = (size_t)GROUPS * 4 * PARTIAL * sizeof(float);
    if (ws_size >= need4) {
        float* ws = (float*)d_ws;
        hipLaunchKernelGGL((la_kv_dma<4>), dim3(4, GROUPS), dim3(256), 0, stream,
                           Kg, Vg, Mg, ws);
        hipLaunchKernelGGL((la_out_mfma<4>), dim3(LSPLITS, GROUPS), dim3(256), 0, stream,
                           Qg, ws, Og);
    } else {
        hipLaunchKernelGGL(la_fused_kernel, dim3(GROUPS), dim3(256), 0, stream,
                           Qg, Kg, Vg, Mg, Og);
    }
}